// Round 1
// baseline (3208.542 us; speedup 1.0000x reference)
//
#include <hip/hip_runtime.h>

typedef float f32x4 __attribute__((ext_vector_type(4)));
typedef short s16x8 __attribute__((ext_vector_type(8)));
typedef __bf16 bf16x8 __attribute__((ext_vector_type(8)));

__device__ __forceinline__ unsigned short f2bf(float f) {
    unsigned int u = __builtin_bit_cast(unsigned int, f);
    u += 0x7FFFu + ((u >> 16) & 1u);
    return (unsigned short)(u >> 16);
}

__device__ __forceinline__ f32x4 MFMA(s16x8 a, s16x8 b, f32x4 c) {
    return __builtin_amdgcn_mfma_f32_16x16x32_bf16(
        __builtin_bit_cast(bf16x8, a), __builtin_bit_cast(bf16x8, b), c, 0, 0, 0);
}

__device__ __forceinline__ float sigm(float v) {
    return __builtin_amdgcn_rcpf(1.f + __builtin_amdgcn_exp2f(-1.4426950408889634f * v));
}
__device__ __forceinline__ float tanh_(float v) {
    return 2.f * __builtin_amdgcn_rcpf(1.f + __builtin_amdgcn_exp2f(-2.8853900817779268f * v)) - 1.f;
}

// ---------------- prologue kernels ----------------

// WC[j,f] = sum_e Wih1[j,e] * W_enc[e,f]   (encoder folded into layer-1 input weights)
// benc[j] = sum_e Wih1[j,e] * b_enc[e]
__global__ void wc_kernel(const float* __restrict__ Wih1, const float* __restrict__ W_enc,
                          const float* __restrict__ b_enc, float* __restrict__ WC,
                          float* __restrict__ benc) {
    int i = blockIdx.x * 256 + threadIdx.x;
    if (i >= 1024 * 35) return;
    int j = i / 35;
    int f = i - j * 35;
    const float* wr = Wih1 + j * 256;
    float s = 0.f;
    if (f < 34) {
        for (int e = 0; e < 256; ++e) s += wr[e] * W_enc[e * 34 + f];
        WC[j * 34 + f] = s;
    } else {
        for (int e = 0; e < 256; ++e) s += wr[e] * b_enc[e];
        benc[j] = s;
    }
}

// Pack W (row-major [rows, srcK]) into bf16 MFMA B-fragment order:
// dst[((nt*KK + kk)*64 + lane)*8 + j] = W[nt*16 + (lane&15)][kk*32 + (lane>>4)*8 + j]
__global__ void pack_kernel(const float* __restrict__ src, unsigned short* __restrict__ dst,
                            int ntiles, int KK, int srcRows, int srcK) {
    int idx = blockIdx.x * 256 + threadIdx.x;
    int total = ntiles * KK * 64;
    if (idx >= total) return;
    int lane = idx & 63;
    int row = (idx / (64 * KK)) * 16 + (lane & 15);
    int kk = (idx >> 6) % KK;
    int kbase = kk * 32 + ((lane >> 4) & 3) * 8;
    s16x8 v;
    #pragma unroll
    for (int j = 0; j < 8; ++j) {
        int k = kbase + j;
        float fv = (row < srcRows && k < srcK) ? src[row * srcK + k] : 0.f;
        v[j] = (short)f2bf(fv);
    }
    *(s16x8*)(dst + (long)idx * 8) = v;
}

__global__ void bias_kernel(const float* bih1, const float* bhh1, const float* benc,
                            const float* bih2, const float* bhh2, const float* b_dec,
                            float* bs1a, float* bs1b, float* bs2, float* bdec) {
    int j = blockIdx.x * 256 + threadIdx.x;
    if (j < 1024) {
        float s = bih1[j] + bhh1[j];
        bs1a[j] = s + benc[j];  // observed steps (includes folded b_enc term)
        bs1b[j] = s;            // future steps
        bs2[j] = bih2[j] + bhh2[j];
    }
    if (j < 48) bdec[j] = (j < 34) ? b_dec[j] : 0.f;
}

// ---------------- fused LSTM kernel ----------------

template <int KK>
__device__ __forceinline__ void gemm_part(const unsigned short* Ab, int astride,
                                          const unsigned short* __restrict__ pW, int ntb,
                                          int ln15, int quad, int lane, f32x4 (&acc)[4][4]) {
    #pragma unroll
    for (int kk = 0; kk < KK; ++kk) {
        s16x8 a[4];
        #pragma unroll
        for (int mt = 0; mt < 4; ++mt)
            a[mt] = *(const s16x8*)(Ab + (mt * 16 + ln15) * astride + kk * 32 + quad * 8);
        #pragma unroll
        for (int g = 0; g < 4; ++g) {
            s16x8 b = *(const s16x8*)(pW + (((g * 16 + ntb) * KK + kk) * 64 + lane) * 8);
            #pragma unroll
            for (int mt = 0; mt < 4; ++mt)
                acc[g][mt] = MFMA(a[mt], b, acc[g][mt]);
        }
    }
}

// One LSTM cell for this block's 64 rows. Reads Ain (input path) and Ahid (hidden path)
// from LDS, weights from packed global (L2-resident), updates fp32 c-state in regs,
// writes new h (bf16) into Hout. Barriers inside (uniform control flow).
template <int KKIN>
__device__ __forceinline__ void lstm_cell_step(
    const unsigned short* Ain, int ainStride, const unsigned short* __restrict__ pWin,
    const unsigned short* Ahid, const unsigned short* __restrict__ pWhid,
    const float* Lbias, float (&cst)[2][4][4], unsigned short* Hout,
    int wave, int lane, int ln15, int quad) {
    unsigned int hp[2][8];
    #pragma unroll
    for (int s = 0; s < 2; ++s) {
        f32x4 acc[4][4];
        #pragma unroll
        for (int g = 0; g < 4; ++g)
            #pragma unroll
            for (int mt = 0; mt < 4; ++mt)
                acc[g][mt] = f32x4{0.f, 0.f, 0.f, 0.f};
        const int ntb = wave * 2 + s;  // within-gate-group N-tile
        gemm_part<KKIN>(Ain, ainStride, pWin, ntb, ln15, quad, lane, acc);
        gemm_part<8>(Ahid, 264, pWhid, ntb, ln15, quad, lane, acc);
        const int colB = wave * 32 + s * 16 + ln15;
        const float bi = Lbias[colB], bff = Lbias[256 + colB];
        const float bg = Lbias[512 + colB], bo = Lbias[768 + colB];
        #pragma unroll
        for (int mt = 0; mt < 4; ++mt) {
            #pragma unroll
            for (int r = 0; r < 4; ++r) {
                float iv = acc[0][mt][r] + bi;
                float fv = acc[1][mt][r] + bff;
                float gv = acc[2][mt][r] + bg;
                float ov = acc[3][mt][r] + bo;
                float cn = sigm(fv) * cst[s][mt][r] + sigm(iv) * tanh_(gv);
                cst[s][mt][r] = cn;
                float hv = sigm(ov) * tanh_(cn);
                unsigned int hb = (unsigned int)f2bf(hv);
                if ((r & 1) == 0) hp[s][mt * 2 + (r >> 1)] = hb;
                else              hp[s][mt * 2 + (r >> 1)] |= (hb << 16);
            }
        }
    }
    __syncthreads();  // all waves done reading h-buffers
    #pragma unroll
    for (int s = 0; s < 2; ++s)
        #pragma unroll
        for (int mt = 0; mt < 4; ++mt)
            #pragma unroll
            for (int r = 0; r < 4; ++r)
                Hout[(mt * 16 + quad * 4 + r) * 264 + wave * 32 + s * 16 + ln15] =
                    (unsigned short)(hp[s][mt * 2 + (r >> 1)] >> ((r & 1) * 16));
    __syncthreads();  // new h visible
}

__global__ __launch_bounds__(512, 2) void lstm_fused(
    const float* __restrict__ x,
    const unsigned short* __restrict__ pWC,
    const unsigned short* __restrict__ pWih1,
    const unsigned short* __restrict__ pWhh1,
    const unsigned short* __restrict__ pWih2,
    const unsigned short* __restrict__ pWhh2,
    const unsigned short* __restrict__ pWdec,
    const float* __restrict__ gb1a, const float* __restrict__ gb1b,
    const float* __restrict__ gb2, const float* __restrict__ gbd,
    float* __restrict__ out) {
    extern __shared__ unsigned char smem[];
    unsigned short* h1buf = (unsigned short*)smem;     // 64 x 264 bf16 (pad +8: bank-balanced b128)
    unsigned short* h2buf = h1buf + 64 * 264;
    unsigned short* xbuf  = h2buf + 64 * 264;          // 64 x 72 bf16 (34 cols + zero pad)
    float* Lb1a = (float*)(xbuf + 64 * 72);
    float* Lb1b = Lb1a + 1024;
    float* Lb2  = Lb1b + 1024;
    float* Lbd  = Lb2 + 1024;                          // 48

    const int tid = threadIdx.x;
    const int wave = tid >> 6;
    const int lane = tid & 63;
    const int ln15 = lane & 15;
    const int quad = lane >> 4;
    const int m0 = blockIdx.x * 64;

    for (int i = tid; i < 64 * 264; i += 512) { h1buf[i] = 0; h2buf[i] = 0; }
    for (int i = tid; i < 64 * 72; i += 512) xbuf[i] = 0;
    for (int i = tid; i < 1024; i += 512) { Lb1a[i] = gb1a[i]; Lb1b[i] = gb1b[i]; Lb2[i] = gb2[i]; }
    if (tid < 48) Lbd[tid] = gbd[tid];

    float c1[2][4][4], c2[2][4][4];
    #pragma unroll
    for (int s = 0; s < 2; ++s)
        #pragma unroll
        for (int mt = 0; mt < 4; ++mt)
            #pragma unroll
            for (int r = 0; r < 4; ++r) { c1[s][mt][r] = 0.f; c2[s][mt][r] = 0.f; }
    f32x4 dAcc[4];  // decoder cumsum accumulator (waves 0..2)

    __syncthreads();

    #pragma unroll 1
    for (int t = 0; t < 19; ++t) {
        const bool obs = (t < 10);
        if (obs) {
            // stage x_t -> xbuf (bf16, zero-padded to 64 cols)
            for (int i = tid; i < 64 * 34; i += 512) {
                int r = i / 34;
                int f = i - r * 34;
                xbuf[r * 72 + f] = f2bf(x[(m0 + r) * 340 + t * 34 + f]);
            }
            __syncthreads();
            lstm_cell_step<2>(xbuf, 72, pWC, h1buf, pWhh1, Lb1a, c1, h1buf, wave, lane, ln15, quad);
        } else {
            // future: layer-1 input is previous h2
            lstm_cell_step<8>(h2buf, 264, pWih1, h1buf, pWhh1, Lb1b, c1, h1buf, wave, lane, ln15, quad);
        }
        lstm_cell_step<8>(h1buf, 264, pWih2, h2buf, pWhh2, Lb2, c2, h2buf, wave, lane, ln15, quad);

        if (t >= 9) {
            const int tout = t - 9;
            if (wave < 3) {  // decoder: dec = h2 @ W_dec^T + b_dec ; cumsum ; +x[:,9,:]
                f32x4 d[4];
                #pragma unroll
                for (int mt = 0; mt < 4; ++mt) d[mt] = f32x4{0.f, 0.f, 0.f, 0.f};
                #pragma unroll
                for (int kk = 0; kk < 8; ++kk) {
                    s16x8 b = *(const s16x8*)(pWdec + ((wave * 8 + kk) * 64 + lane) * 8);
                    #pragma unroll
                    for (int mt = 0; mt < 4; ++mt) {
                        s16x8 a = *(const s16x8*)(h2buf + (mt * 16 + ln15) * 264 + kk * 32 + quad * 8);
                        d[mt] = MFMA(a, b, d[mt]);
                    }
                }
                const int col = wave * 16 + ln15;
                const bool valid = (col < 34);
                const float bd = Lbd[col];
                #pragma unroll
                for (int mt = 0; mt < 4; ++mt) {
                    #pragma unroll
                    for (int r = 0; r < 4; ++r) {
                        const int row = m0 + mt * 16 + quad * 4 + r;
                        float v = d[mt][r] + bd;
                        if (tout == 0) {
                            float xr = valid ? x[row * 340 + 306 + col] : 0.f;
                            dAcc[mt][r] = v + xr;
                        } else {
                            dAcc[mt][r] += v;
                        }
                        if (valid) out[row * 340 + tout * 34 + col] = dAcc[mt][r];
                    }
                }
            }
        }
    }
}

// ---------------- launch ----------------

extern "C" void kernel_launch(void* const* d_in, const int* in_sizes, int n_in,
                              void* d_out, int out_size, void* d_ws, size_t ws_size,
                              hipStream_t stream) {
    const float* x     = (const float*)d_in[0];
    const float* W_enc = (const float*)d_in[1];
    const float* b_enc = (const float*)d_in[2];
    const float* Wih1  = (const float*)d_in[3];
    const float* Whh1  = (const float*)d_in[4];
    const float* bih1  = (const float*)d_in[5];
    const float* bhh1  = (const float*)d_in[6];
    const float* Wih2  = (const float*)d_in[7];
    const float* Whh2  = (const float*)d_in[8];
    const float* bih2  = (const float*)d_in[9];
    const float* bhh2  = (const float*)d_in[10];
    const float* W_dec = (const float*)d_in[11];
    const float* b_dec = (const float*)d_in[12];
    float* out = (float*)d_out;

    unsigned char* w = (unsigned char*)d_ws;
    float* WC   = (float*)(w + 0);         // 1024*34*4 = 139264
    float* benc = (float*)(w + 139264);    // 4096
    float* bs1a = (float*)(w + 143360);
    float* bs1b = (float*)(w + 147456);
    float* bs2  = (float*)(w + 151552);
    float* bdec = (float*)(w + 155648);    // 192 (+pad)
    unsigned short* pWC   = (unsigned short*)(w + 155904);   // 131072
    unsigned short* pWih1 = (unsigned short*)(w + 286976);   // 524288
    unsigned short* pWhh1 = (unsigned short*)(w + 811264);
    unsigned short* pWih2 = (unsigned short*)(w + 1335552);
    unsigned short* pWhh2 = (unsigned short*)(w + 1859840);
    unsigned short* pWdec = (unsigned short*)(w + 2384128);  // 24576

    wc_kernel<<<140, 256, 0, stream>>>(Wih1, W_enc, b_enc, WC, benc);
    pack_kernel<<<32, 256, 0, stream>>>(WC, pWC, 64, 2, 1024, 34);
    pack_kernel<<<128, 256, 0, stream>>>(Wih1, pWih1, 64, 8, 1024, 256);
    pack_kernel<<<128, 256, 0, stream>>>(Whh1, pWhh1, 64, 8, 1024, 256);
    pack_kernel<<<128, 256, 0, stream>>>(Wih2, pWih2, 64, 8, 1024, 256);
    pack_kernel<<<128, 256, 0, stream>>>(Whh2, pWhh2, 64, 8, 1024, 256);
    pack_kernel<<<6, 256, 0, stream>>>(W_dec, pWdec, 3, 8, 34, 256);
    bias_kernel<<<4, 256, 0, stream>>>(bih1, bhh1, benc, bih2, bhh2, b_dec, bs1a, bs1b, bs2, bdec);

    // 89280 B dynamic LDS (> 64 KB static limit); attribute set is not a stream op (capture-safe)
    hipFuncSetAttribute((const void*)lstm_fused, hipFuncAttributeMaxDynamicSharedMemorySize, 89280);
    lstm_fused<<<256, 512, 89280, stream>>>(x, pWC, pWih1, pWhh1, pWih2, pWhh2, pWdec,
                                            bs1a, bs1b, bs2, bdec, out);
}

// Round 3
// 1055.894 us; speedup vs baseline: 3.0387x; 3.0387x over previous
//
#include <hip/hip_runtime.h>

typedef float f32x4 __attribute__((ext_vector_type(4)));
typedef float f32x2 __attribute__((ext_vector_type(2)));
typedef short s16x8 __attribute__((ext_vector_type(8)));
typedef __bf16 bf16x8 __attribute__((ext_vector_type(8)));

__device__ __forceinline__ unsigned short f2bf(float f) {
    unsigned int u = __builtin_bit_cast(unsigned int, f);
    u += 0x7FFFu + ((u >> 16) & 1u);
    return (unsigned short)(u >> 16);
}

__device__ __forceinline__ f32x4 MFMA(s16x8 a, s16x8 b, f32x4 c) {
    return __builtin_amdgcn_mfma_f32_16x16x32_bf16(
        __builtin_bit_cast(bf16x8, a), __builtin_bit_cast(bf16x8, b), c, 0, 0, 0);
}

__device__ __forceinline__ float sigm(float v) {
    return __builtin_amdgcn_rcpf(1.f + __builtin_amdgcn_exp2f(-1.4426950408889634f * v));
}
__device__ __forceinline__ float tanh_(float v) {
    return 2.f * __builtin_amdgcn_rcpf(1.f + __builtin_amdgcn_exp2f(-2.8853900817779268f * v)) - 1.f;
}

// ---------------- prologue kernels ----------------

// WC[j,f] = sum_e Wih1[j,e] * W_enc[e,f]; benc[j] = sum_e Wih1[j,e] * b_enc[e]
__global__ void wc_kernel(const float* __restrict__ Wih1, const float* __restrict__ W_enc,
                          const float* __restrict__ b_enc, float* __restrict__ WC,
                          float* __restrict__ benc) {
    int i = blockIdx.x * 256 + threadIdx.x;
    if (i >= 1024 * 35) return;
    int j = i / 35;
    int f = i - j * 35;
    const float* wr = Wih1 + j * 256;
    float s = 0.f;
    if (f < 34) {
        for (int e = 0; e < 256; ++e) s += wr[e] * W_enc[e * 34 + f];
        WC[j * 34 + f] = s;
    } else {
        for (int e = 0; e < 256; ++e) s += wr[e] * b_enc[e];
        benc[j] = s;
    }
}

// Pack W (row-major [srcRows, srcK]) into per-wave-sequential bf16 B-frag streams:
// linear s16x8 index ((ntb*KK + kk)*G + g)*64 + lane holds
//   W[g*gStride + ntb*16 + (lane&15)][kk*32 + (lane>>4)*8 + j]  (0 outside bounds)
__global__ void pack_kernel(const float* __restrict__ src, unsigned short* __restrict__ dst,
                            int NTB, int KK, int G, int gStride, int srcRows, int srcK) {
    int idx = blockIdx.x * 256 + threadIdx.x;
    int total = NTB * KK * G * 64;
    if (idx >= total) return;
    int lane = idx & 63, q = idx >> 6;
    int g = q % G; q /= G;
    int kk = q % KK;
    int ntb = q / KK;
    int row = g * gStride + ntb * 16 + (lane & 15);
    int kbase = kk * 32 + ((lane >> 4) & 3) * 8;
    s16x8 v;
    #pragma unroll
    for (int j = 0; j < 8; ++j) {
        int k = kbase + j;
        float fv = (row < srcRows && k < srcK) ? src[row * srcK + k] : 0.f;
        v[j] = (short)f2bf(fv);
    }
    *(s16x8*)(dst + (long)idx * 8) = v;
}

__global__ void bias_kernel(const float* bih1, const float* bhh1, const float* benc,
                            const float* bih2, const float* bhh2, const float* b_dec,
                            float* bs1a, float* bs1b, float* bs2, float* bdec) {
    int j = blockIdx.x * 256 + threadIdx.x;
    if (j < 1024) {
        float s = bih1[j] + bhh1[j];
        bs1a[j] = s + benc[j];
        bs1b[j] = s;
        bs2[j] = bih2[j] + bhh2[j];
    }
    if (j < 48) bdec[j] = (j < 34) ? b_dec[j] : 0.f;
}

// ---------------- fused LSTM kernel ----------------

// One LSTM cell for this block's 64 rows. Input path (kkin k-tiles of 32) then hidden
// path (8 k-tiles) as one software-pipelined stream; depth-2 B/A ping-pong registers.
__device__ __forceinline__ void cell_step(
    const unsigned short* Ain, int ainStride, int kkin,
    const unsigned short* Ahid,
    const unsigned short* __restrict__ pWin,
    const unsigned short* __restrict__ pWhid,
    const float* Lbias, float (&cst)[2][4][4], unsigned short* Hout,
    int wave, int lane, int ln15, int quad) {
    unsigned int hp[2][8];
    #pragma unroll
    for (int s = 0; s < 2; ++s) {
        const int ntb = wave * 2 + s;
        const s16x8* wIn  = (const s16x8*)pWin  + ntb * kkin * 256 + lane;
        const s16x8* wHid = (const s16x8*)pWhid + ntb * 8 * 256 + lane;
        f32x4 acc[4][4];
        #pragma unroll
        for (int g = 0; g < 4; ++g)
            #pragma unroll
            for (int mt = 0; mt < 4; ++mt) acc[g][mt] = f32x4{0.f, 0.f, 0.f, 0.f};
        const int total = kkin + 8;  // always even (10 or 16)
        s16x8 B0[4], B1[4], A0[4], A1[4];
        {   // t = 0 (always input path)
            B0[0] = wIn[0]; B0[1] = wIn[64]; B0[2] = wIn[128]; B0[3] = wIn[192];
            #pragma unroll
            for (int mt = 0; mt < 4; ++mt)
                A0[mt] = *(const s16x8*)(Ain + (mt * 16 + ln15) * ainStride + quad * 8);
        }
        #pragma unroll 1
        for (int t = 0; t < total; t += 2) {
            {   // prefetch t+1 -> B1/A1
                int u = t + 1;
                const s16x8* p = (u < kkin) ? (wIn + u * 256) : (wHid + (u - kkin) * 256);
                B1[0] = p[0]; B1[1] = p[64]; B1[2] = p[128]; B1[3] = p[192];
                const unsigned short* ap; int st;
                if (u < kkin) { ap = Ain + u * 32; st = ainStride; }
                else          { ap = Ahid + (u - kkin) * 32; st = 264; }
                #pragma unroll
                for (int mt = 0; mt < 4; ++mt)
                    A1[mt] = *(const s16x8*)(ap + (mt * 16 + ln15) * st + quad * 8);
            }
            #pragma unroll
            for (int g = 0; g < 4; ++g)
                #pragma unroll
                for (int mt = 0; mt < 4; ++mt) acc[g][mt] = MFMA(A0[mt], B0[g], acc[g][mt]);
            if (t + 2 < total) {  // prefetch t+2 -> B0/A0
                int u = t + 2;
                const s16x8* p = (u < kkin) ? (wIn + u * 256) : (wHid + (u - kkin) * 256);
                B0[0] = p[0]; B0[1] = p[64]; B0[2] = p[128]; B0[3] = p[192];
                const unsigned short* ap; int st;
                if (u < kkin) { ap = Ain + u * 32; st = ainStride; }
                else          { ap = Ahid + (u - kkin) * 32; st = 264; }
                #pragma unroll
                for (int mt = 0; mt < 4; ++mt)
                    A0[mt] = *(const s16x8*)(ap + (mt * 16 + ln15) * st + quad * 8);
            }
            #pragma unroll
            for (int g = 0; g < 4; ++g)
                #pragma unroll
                for (int mt = 0; mt < 4; ++mt) acc[g][mt] = MFMA(A1[mt], B1[g], acc[g][mt]);
        }
        const int colB = ntb * 16 + ln15;
        const float bi = Lbias[colB], bff = Lbias[256 + colB];
        const float bg = Lbias[512 + colB], bo = Lbias[768 + colB];
        #pragma unroll
        for (int mt = 0; mt < 4; ++mt) {
            #pragma unroll
            for (int r = 0; r < 4; ++r) {
                float iv = acc[0][mt][r] + bi;
                float fv = acc[1][mt][r] + bff;
                float gv = acc[2][mt][r] + bg;
                float ov = acc[3][mt][r] + bo;
                float cn = sigm(fv) * cst[s][mt][r] + sigm(iv) * tanh_(gv);
                cst[s][mt][r] = cn;
                float hv = sigm(ov) * tanh_(cn);
                unsigned int hb = (unsigned int)f2bf(hv);
                if ((r & 1) == 0) hp[s][mt * 2 + (r >> 1)] = hb;
                else              hp[s][mt * 2 + (r >> 1)] |= (hb << 16);
            }
        }
    }
    __syncthreads();  // all waves done reading h-buffers
    #pragma unroll
    for (int s = 0; s < 2; ++s)
        #pragma unroll
        for (int mt = 0; mt < 4; ++mt)
            #pragma unroll
            for (int r = 0; r < 4; ++r)
                Hout[(mt * 16 + quad * 4 + r) * 264 + (wave * 2 + s) * 16 + ln15] =
                    (unsigned short)(hp[s][mt * 2 + (r >> 1)] >> ((r & 1) * 16));
    __syncthreads();  // new h visible
}

__global__ __launch_bounds__(512, 2) void lstm_fused(
    const float* __restrict__ x,
    const unsigned short* __restrict__ pWC,
    const unsigned short* __restrict__ pWih1,
    const unsigned short* __restrict__ pWhh1,
    const unsigned short* __restrict__ pWih2,
    const unsigned short* __restrict__ pWhh2,
    const unsigned short* __restrict__ pWdec,
    const float* __restrict__ gb1a, const float* __restrict__ gb1b,
    const float* __restrict__ gb2, const float* __restrict__ gbd,
    float* __restrict__ out) {
    extern __shared__ unsigned char smem[];
    unsigned short* h1buf = (unsigned short*)smem;            // 64 x 264 bf16 = 33792 B
    unsigned short* h2buf = h1buf + 64 * 264;                 // 33792 B
    unsigned char* scratch = (unsigned char*)(h2buf + 64 * 264);  // 12288 B shared region:
    unsigned short* xbuf = (unsigned short*)scratch;          //   obs: 64 x 72 bf16 (zero-padded)
    float* dOut = (float*)scratch;                            //   dec: 64 x 48 f32
    float* Lb1a = (float*)(scratch + 12288);
    float* Lb1b = Lb1a + 1024;
    float* Lb2  = Lb1b + 1024;
    float* Lbd  = Lb2 + 1024;  // 48 used

    const int tid = threadIdx.x;
    const int wave = tid >> 6;
    const int lane = tid & 63;
    const int ln15 = lane & 15;
    const int quad = lane >> 4;
    const int m0 = blockIdx.x * 64;

    for (int i = tid; i < 64 * 264; i += 512) { h1buf[i] = 0; h2buf[i] = 0; }
    for (int i = tid; i < 3072; i += 512) ((int*)scratch)[i] = 0;
    for (int i = tid; i < 1024; i += 512) { Lb1a[i] = gb1a[i]; Lb1b[i] = gb1b[i]; Lb2[i] = gb2[i]; }
    if (tid < 48) Lbd[tid] = gbd[tid];

    float c1[2][4][4], c2[2][4][4];
    #pragma unroll
    for (int s = 0; s < 2; ++s)
        #pragma unroll
        for (int mt = 0; mt < 4; ++mt)
            #pragma unroll
            for (int r = 0; r < 4; ++r) { c1[s][mt][r] = 0.f; c2[s][mt][r] = 0.f; }
    f32x4 dAcc[4];  // decoder cumsum accumulator (waves 0..2)

    __syncthreads();

    #pragma unroll 1
    for (int t = 0; t < 19; ++t) {
        if (t < 10) {
            // stage x_t -> xbuf (bf16; cols 34..63 stay zero). Non-temporal: keep L2 for weights.
            for (int i = tid; i < 1088; i += 512) {
                int r = i / 17, p = i - r * 17;
                f32x2 v = __builtin_nontemporal_load((const f32x2*)(x + (m0 + r) * 340 + t * 34) + p);
                xbuf[r * 72 + p * 2]     = f2bf(v.x);
                xbuf[r * 72 + p * 2 + 1] = f2bf(v.y);
            }
            __syncthreads();
            cell_step(xbuf, 72, 2, h1buf, pWC, pWhh1, Lb1a, c1, h1buf, wave, lane, ln15, quad);
        } else {
            cell_step(h2buf, 264, 8, h1buf, pWih1, pWhh1, Lb1b, c1, h1buf, wave, lane, ln15, quad);
        }
        cell_step(h1buf, 264, 8, h2buf, pWih2, pWhh2, Lb2, c2, h2buf, wave, lane, ln15, quad);

        if (t >= 9) {
            const int tout = t - 9;
            if (wave < 3) {  // decoder: dec = h2 @ W_dec^T + b_dec ; cumsum; +x[:,9,:] at tout 0
                f32x4 d[4];
                #pragma unroll
                for (int mt = 0; mt < 4; ++mt) d[mt] = f32x4{0.f, 0.f, 0.f, 0.f};
                #pragma unroll
                for (int kk = 0; kk < 8; ++kk) {
                    s16x8 b = *((const s16x8*)pWdec + (wave * 8 + kk) * 64 + lane);
                    #pragma unroll
                    for (int mt = 0; mt < 4; ++mt) {
                        s16x8 a = *(const s16x8*)(h2buf + (mt * 16 + ln15) * 264 + kk * 32 + quad * 8);
                        d[mt] = MFMA(a, b, d[mt]);
                    }
                }
                const int col = wave * 16 + ln15;
                const bool valid = (col < 34);
                const float bd = Lbd[col];
                #pragma unroll
                for (int mt = 0; mt < 4; ++mt) {
                    #pragma unroll
                    for (int r = 0; r < 4; ++r) {
                        const int rloc = mt * 16 + quad * 4 + r;
                        float v = d[mt][r] + bd;
                        if (tout == 0) {
                            float xr = valid ? __builtin_nontemporal_load(x + (m0 + rloc) * 340 + 306 + col) : 0.f;
                            dAcc[mt][r] = v + xr;
                        } else {
                            dAcc[mt][r] += v;
                        }
                        dOut[rloc * 48 + col] = dAcc[mt][r];
                    }
                }
            }
            __syncthreads();
            // contiguous per-row non-temporal stores (write-combine friendly)
            for (int i = tid; i < 1088; i += 512) {
                int r = i / 17, p = i - r * 17;
                f32x2 v = *(const f32x2*)(dOut + r * 48 + p * 2);
                __builtin_nontemporal_store(v, (f32x2*)(out + (m0 + r) * 340 + tout * 34) + p);
            }
            // no barrier needed: dOut is rewritten only after cell barriers of step t+1
        }
    }
}

// ---------------- launch ----------------

extern "C" void kernel_launch(void* const* d_in, const int* in_sizes, int n_in,
                              void* d_out, int out_size, void* d_ws, size_t ws_size,
                              hipStream_t stream) {
    const float* x     = (const float*)d_in[0];
    const float* W_enc = (const float*)d_in[1];
    const float* b_enc = (const float*)d_in[2];
    const float* Wih1  = (const float*)d_in[3];
    const float* Whh1  = (const float*)d_in[4];
    const float* bih1  = (const float*)d_in[5];
    const float* bhh1  = (const float*)d_in[6];
    const float* Wih2  = (const float*)d_in[7];
    const float* Whh2  = (const float*)d_in[8];
    const float* bih2  = (const float*)d_in[9];
    const float* bhh2  = (const float*)d_in[10];
    const float* W_dec = (const float*)d_in[11];
    const float* b_dec = (const float*)d_in[12];
    float* out = (float*)d_out;

    unsigned char* w = (unsigned char*)d_ws;
    float* WC   = (float*)(w + 0);         // 139264
    float* benc = (float*)(w + 139264);    // 4096
    float* bs1a = (float*)(w + 143360);
    float* bs1b = (float*)(w + 147456);
    float* bs2  = (float*)(w + 151552);
    float* bdec = (float*)(w + 155648);    // 256
    unsigned short* pWC   = (unsigned short*)(w + 155904);   // 16*2*4*64*16 = 131072
    unsigned short* pWih1 = (unsigned short*)(w + 286976);   // 524288 each
    unsigned short* pWhh1 = (unsigned short*)(w + 811264);
    unsigned short* pWih2 = (unsigned short*)(w + 1335552);
    unsigned short* pWhh2 = (unsigned short*)(w + 1859840);
    unsigned short* pWdec = (unsigned short*)(w + 2384128);  // 24576

    wc_kernel<<<140, 256, 0, stream>>>(Wih1, W_enc, b_enc, WC, benc);
    pack_kernel<<<32, 256, 0, stream>>>(WC, pWC, 16, 2, 4, 256, 1024, 34);
    pack_kernel<<<128, 256, 0, stream>>>(Wih1, pWih1, 16, 8, 4, 256, 1024, 256);
    pack_kernel<<<128, 256, 0, stream>>>(Whh1, pWhh1, 16, 8, 4, 256, 1024, 256);
    pack_kernel<<<128, 256, 0, stream>>>(Wih2, pWih2, 16, 8, 4, 256, 1024, 256);
    pack_kernel<<<128, 256, 0, stream>>>(Whh2, pWhh2, 16, 8, 4, 256, 1024, 256);
    pack_kernel<<<6, 256, 0, stream>>>(W_dec, pWdec, 3, 8, 1, 0, 34, 256);
    bias_kernel<<<4, 256, 0, stream>>>(bih1, bhh1, benc, bih2, bhh2, b_dec, bs1a, bs1b, bs2, bdec);

    hipFuncSetAttribute((const void*)lstm_fused, hipFuncAttributeMaxDynamicSharedMemorySize, 92352);
    lstm_fused<<<256, 512, 92352, stream>>>(x, pWC, pWih1, pWhh1, pWih2, pWhh2, pWdec,
                                            bs1a, bs1b, bs2, bdec, out);
}